// Round 1
// 1729.395 us; speedup vs baseline: 1.5084x; 1.5084x over previous
//
#include <hip/hip_runtime.h>

// ---------------------------------------------------------------------------
// LSTM autoencoder w/ attention, MI355X fp16-MFMA implementation.
// S=128, B=256, IN=H=OUT=1024.  All GEMMs plain fp16 inputs, fp32 accumulate.
// R2: (a) k_step rebuilt as BK=64 x 4-buffer counted-vmcnt pipeline (raw
//     s_barrier, vmcnt(12) steady state) - removes the per-iter vmcnt(0)
//     drain at 1 wave/SIMD.  (b) k_attn rebuilt as MFMA GEMM (A fp16 +
//     fp16 residual for precision), hs staged via source-swizzled
//     global_load_lds, transposed B-fragments via conflict-free 2B LDS reads.
// ---------------------------------------------------------------------------

typedef _Float16 half8 __attribute__((ext_vector_type(8)));
typedef float f32x4 __attribute__((ext_vector_type(4)));

#define S_  128
#define B_  256
#define HDIM 1024
#define BH  262144          // B*H
#define K2  2048            // IN + H

// async global -> LDS, 16B per lane, wave-uniform LDS base
__device__ __forceinline__ void g2l16(void* lds_base, const void* g) {
  __builtin_amdgcn_global_load_lds(
      (const __attribute__((address_space(1))) void*)g,
      (__attribute__((address_space(3))) void*)lds_base, 16, 0, 0);
}

__device__ __forceinline__ float sigmoidf_(float x) {
  return 1.f / (1.f + __expf(-x));
}
__device__ __forceinline__ float tanhf_(float x) {
  float e = __expf(-2.f * fabsf(x));
  float t = (1.f - e) / (1.f + e);
  return x < 0.f ? -t : t;
}

// --------------------------- converters ------------------------------------
__global__ __launch_bounds__(256) void k_cvt(const float* __restrict__ src,
                                             _Float16* __restrict__ dst) {
  size_t i = ((size_t)blockIdx.x * 256 + threadIdx.x) * 8;
  float4 u = *(const float4*)(src + i);
  float4 v = *(const float4*)(src + i + 4);
  half8 h;
  h[0] = u.x; h[1] = u.y; h[2] = u.z; h[3] = u.w;
  h[4] = v.x; h[5] = v.y; h[6] = v.z; h[7] = v.w;
  *(half8*)(dst + i) = h;
}

// Wcat[r][k] = k<1024 ? W_ih[r][k] : W_hh[r][k-1024]   (fp16, [4096][2048])
__global__ __launch_bounds__(256) void k_wcat(const float* __restrict__ Wih,
                                              const float* __restrict__ Whh,
                                              _Float16* __restrict__ Wc) {
  size_t i = ((size_t)blockIdx.x * 256 + threadIdx.x) * 8;
  int r = (int)(i >> 11), k = (int)(i & 2047);
  const float* src = (k < 1024) ? (Wih + (size_t)r * 1024 + k)
                                : (Whh + (size_t)r * 1024 + (k - 1024));
  float4 u = *(const float4*)(src);
  float4 v = *(const float4*)(src + 4);
  half8 h;
  h[0] = u.x; h[1] = u.y; h[2] = u.z; h[3] = u.w;
  h[4] = v.x; h[5] = v.y; h[6] = v.z; h[7] = v.w;
  *(half8*)(Wc + i) = h;
}

// cbuf = c0 ; hs[0] = fp16(h0) ; bias = b_ih + b_hh
__global__ __launch_bounds__(256) void k_init(const float* __restrict__ h0,
                                              const float* __restrict__ c0,
                                              const float* __restrict__ bih,
                                              const float* __restrict__ bhh,
                                              _Float16* __restrict__ hs0,
                                              float* __restrict__ cbuf,
                                              float* __restrict__ bias) {
  int i = blockIdx.x * 256 + threadIdx.x;   // 262144 total
  cbuf[i] = c0[i];
  hs0[i] = (_Float16)h0[i];
  if (i < 4096) bias[i] = bih[i] + bhh[i];
}

// row softmax of attnW [128][128] -> fp16 Ah + fp16 residual Ar
// (Ah + Ar together carry ~fp32 precision of the attention weights)
__global__ __launch_bounds__(64) void k_softmax(const float* __restrict__ W,
                                                _Float16* __restrict__ Ah,
                                                _Float16* __restrict__ Ar) {
  int r = blockIdx.x, lane = threadIdx.x;
  float v0 = W[r * 128 + lane], v1 = W[r * 128 + 64 + lane];
  float m = fmaxf(v0, v1);
  for (int off = 32; off; off >>= 1) m = fmaxf(m, __shfl_xor(m, off));
  float e0 = __expf(v0 - m), e1 = __expf(v1 - m);
  float s = e0 + e1;
  for (int off = 32; off; off >>= 1) s += __shfl_xor(s, off);
  float inv = 1.f / s;
  float a0 = e0 * inv, a1 = e1 * inv;
  _Float16 h0 = (_Float16)a0, h1 = (_Float16)a1;
  Ah[r * 128 + lane] = h0;
  Ah[r * 128 + 64 + lane] = h1;
  Ar[r * 128 + lane] = (_Float16)(a0 - (float)h0);
  Ar[r * 128 + 64 + lane] = (_Float16)(a1 - (float)h1);
}

// --------------------------- fused LSTM step --------------------------------
// gates[B,4H] = [x_t | h_{t-1}] @ Wcat^T + bias, then cell, h -> hs[t+1].
// Block: 64 batch-rows x 16 H-cols x 4 gates. Grid 256 (n-tile-major).
// BK=64, FOUR LDS buffers (16KB each = 64KB), prefetch depth 3, raw
// s_barrier + counted vmcnt(12): loads stay in flight across barriers.
__global__ __launch_bounds__(256) void k_step(const _Float16* __restrict__ Xh,
                                              const _Float16* __restrict__ Wc,
                                              const float* __restrict__ bias,
                                              _Float16* __restrict__ hs,
                                              float* __restrict__ cbuf,
                                              int t) {
  __shared__ char smem[65536];
  const int tid = threadIdx.x;
  const int wave = tid >> 6;
  const int lane = tid & 63;
  const int n_tile = blockIdx.x & 63;   // consecutive bids -> consecutive n (Wc slice stays in one XCD L2)
  const int m_tile = blockIdx.x >> 6;
  const int n0 = n_tile * 16;
  const int m0 = m_tile * 64;

  const _Float16* Xt = Xh + (size_t)t * BH;       // x_t rows, stride 1024
  const _Float16* Hp = hs + (size_t)t * BH;       // h_{t-1} rows, stride 1024

  f32x4 acc[4];
  #pragma unroll
  for (int g = 0; g < 4; ++g) acc[g] = (f32x4){0.f, 0.f, 0.f, 0.f};

  // per-thread staging source offsets (elements), 4 16B-slots per thread.
  // buffer layout: A tile 64 rows x 128B (8 chunks, XOR c^(r&7)) = 8KB,
  //                B tile 64 gate-rows x 128B = 8KB.  LDS slot = s*16.
  int offA[2], offB[2];
  #pragma unroll
  for (int q = 0; q < 4; ++q) {
    int s = q * 256 + tid;
    if (q < 2) {                       // s in [0,512): A tile
      int r = s >> 3, c = s & 7;
      int kc = c ^ (r & 7);
      offA[q] = (m0 + r) * 1024 + kc * 8;
    } else {                           // s in [512,1024): B tile
      int sb = s - 512;
      int r = sb >> 3, c = sb & 7;
      int kc = c ^ (r & 7);
      int row = (r >> 4) * 1024 + n0 + (r & 15);
      offB[q - 2] = row * 2048 + kc * 8;
    }
  }

  auto stage = [&](int buf, int k0) {
    char* base = smem + buf * 16384;
    const _Float16* Ab = (k0 < 1024) ? (Xt + k0) : (Hp + (k0 - 1024));
    #pragma unroll
    for (int q = 0; q < 4; ++q) {
      char* dst = base + (q * 4 + wave) * 1024;     // wave-uniform
      if (q < 2) g2l16(dst, Ab + offA[q]);
      else       g2l16(dst, Wc + offB[q - 2] + k0);
    }
  };

  // per-lane LDS read offsets (constant across iters)
  const int ra = wave * 16 + (lane & 15);
  const int kcl = lane >> 4;                        // 0..3
  const int aoff0 = ra * 128 + ((kcl ^ (ra & 7)) * 16);
  const int aoff1 = ra * 128 + (((kcl + 4) ^ (ra & 7)) * 16);
  int boff0[4], boff1[4];
  #pragma unroll
  for (int g = 0; g < 4; ++g) {
    int rb = g * 16 + (lane & 15);
    boff0[g] = 8192 + rb * 128 + ((kcl ^ (rb & 7)) * 16);
    boff1[g] = 8192 + rb * 128 + (((kcl + 4) ^ (rb & 7)) * 16);
  }

  stage(0, 0);
  stage(1, 64);
  stage(2, 128);

  #pragma unroll
  for (int iter = 0; iter < 32; ++iter) {
    if (iter < 29) stage((iter + 3) & 3, (iter + 3) * 64);
    // wait for THIS buffer's 4 loads (oldest); keep the rest in flight.
    if (iter < 29)       asm volatile("s_waitcnt vmcnt(12)" ::: "memory");
    else if (iter == 29) asm volatile("s_waitcnt vmcnt(8)"  ::: "memory");
    else if (iter == 30) asm volatile("s_waitcnt vmcnt(4)"  ::: "memory");
    else                 asm volatile("s_waitcnt vmcnt(0)"  ::: "memory");
    __builtin_amdgcn_s_barrier();                   // buffer ready (all waves)
    const char* At = smem + (iter & 3) * 16384;
    half8 a0 = *(const half8*)(At + aoff0);
    half8 a1 = *(const half8*)(At + aoff1);
    #pragma unroll
    for (int g = 0; g < 4; ++g) {
      half8 b0 = *(const half8*)(At + boff0[g]);
      acc[g] = __builtin_amdgcn_mfma_f32_16x16x32_f16(a0, b0, acc[g], 0, 0, 0);
    }
    #pragma unroll
    for (int g = 0; g < 4; ++g) {
      half8 b1 = *(const half8*)(At + boff1[g]);
      acc[g] = __builtin_amdgcn_mfma_f32_16x16x32_f16(a1, b1, acc[g], 0, 0, 0);
    }
    __builtin_amdgcn_s_barrier();                   // all waves done reading
  }

  // epilogue: lane owns 4 (m,n) positions with all 4 gates in-register.
  // C layout: col = lane&15, row = (lane>>4)*4 + reg.
  int n = n0 + (lane & 15);
  float bi = bias[n], bf = bias[1024 + n], bg = bias[2048 + n], bo = bias[3072 + n];
  int mrow0 = m0 + wave * 16 + (lane >> 4) * 4;
  _Float16* hnext = hs + (size_t)(t + 1) * BH;
  #pragma unroll
  for (int r = 0; r < 4; ++r) {
    size_t idx = (size_t)(mrow0 + r) * 1024 + n;
    float gi = sigmoidf_(acc[0][r] + bi);
    float gf = sigmoidf_(acc[1][r] + bf);
    float gg = tanhf_(acc[2][r] + bg);
    float go = sigmoidf_(acc[3][r] + bo);
    float c = gf * cbuf[idx] + gi * gg;
    cbuf[idx] = c;
    hnext[idx] = (_Float16)(go * tanhf_(c));
  }
}

// --------------------------- attention mix (MFMA) ---------------------------
// att[x, n] = sum_y (Ah+Ar)[x,y] * hs[y+1, n],  x,y in [0,128), n in [0,262144).
// Block: M=128 (all x) x N=256 cols, K=128 in 4 chunks of 32.  4 waves split N.
// LDS: [0,64K) A (Ah | Ar), 16-chunk XOR swizzle c^(r&15) per 256B row.
//      [64K,128K) 4 hs chunks [32 y][512B], source chunk-XOR c^( ((y>>3)&3)<<1 )
//      so the transposed 2B column reads for B-fragments are conflict-free.
__global__ __launch_bounds__(256) void k_attn(const _Float16* __restrict__ Ah,
                                              const _Float16* __restrict__ Ar,
                                              const _Float16* __restrict__ hs,
                                              _Float16* __restrict__ att) {
  __shared__ char smem[131072];
  const int tid = threadIdx.x;
  const int wave = tid >> 6;
  const int lane = tid & 63;
  const int n0 = blockIdx.x * 256;

  // ---- stage A (Ah then Ar), 4096 slots, 16 per thread, all issued now ----
  #pragma unroll
  for (int q = 0; q < 16; ++q) {
    int s = q * 256 + tid;
    char* dst = smem + (q * 4 + wave) * 1024;
    if (q < 8) {
      int r = s >> 4;
      int cl = (s & 15) ^ (r & 15);
      g2l16(dst, Ah + r * 128 + cl * 8);
    } else {
      int s2 = s - 2048;
      int r = s2 >> 4;
      int cl = (s2 & 15) ^ (r & 15);
      g2l16(dst, Ar + r * 128 + cl * 8);
    }
  }
  // ---- stage 4 hs chunks (16KB each), 4 slots per thread per chunk --------
  #pragma unroll
  for (int ch = 0; ch < 4; ++ch) {
    char* base = smem + 65536 + ch * 16384;
    #pragma unroll
    for (int q = 0; q < 4; ++q) {
      int s = q * 256 + tid;
      int y = s >> 5, cp = s & 31;
      int cl = cp ^ (((y >> 3) & 3) << 1);
      g2l16(base + (q * 4 + wave) * 1024,
            hs + (size_t)(1 + ch * 32 + y) * BH + n0 + cl * 8);
    }
  }

  f32x4 acc[8][4];
  #pragma unroll
  for (int m = 0; m < 8; ++m)
    #pragma unroll
    for (int nf = 0; nf < 4; ++nf) acc[m][nf] = (f32x4){0.f, 0.f, 0.f, 0.f};

  const int yg = lane >> 4;             // 0..3 : k-group of the wave

  #pragma unroll
  for (int ch = 0; ch < 4; ++ch) {
    // A(16 loads) is oldest, then chunks: wait A + chunks<=ch done.
    if (ch == 0)      asm volatile("s_waitcnt vmcnt(12)" ::: "memory");
    else if (ch == 1) asm volatile("s_waitcnt vmcnt(8)"  ::: "memory");
    else if (ch == 2) asm volatile("s_waitcnt vmcnt(4)"  ::: "memory");
    else              asm volatile("s_waitcnt vmcnt(0)"  ::: "memory");
    __builtin_amdgcn_s_barrier();

    const char* cb = smem + 65536 + ch * 16384;
    // B-fragments: transposed column reads.  lane's column n, rows
    // y = yg*8 + j.  Physical chunk = (n>>3) ^ (yg<<1)  (matches staging).
    half8 b[4];
    #pragma unroll
    for (int nf = 0; nf < 4; ++nf) {
      int n = wave * 64 + nf * 16 + (lane & 15);
      const char* col = cb + (((n >> 3) ^ (yg << 1)) * 16) + (n & 7) * 2;
      #pragma unroll
      for (int j = 0; j < 8; ++j)
        b[nf][j] = *(const _Float16*)(col + (yg * 8 + j) * 512);
    }
    #pragma unroll
    for (int m = 0; m < 8; ++m) {
      int x = m * 16 + (lane & 15);
      int sw = ((ch * 4 + yg) ^ (x & 15)) * 16;
      half8 ah = *(const half8*)(smem + x * 256 + sw);
      half8 ar = *(const half8*)(smem + 32768 + x * 256 + sw);
      #pragma unroll
      for (int nf = 0; nf < 4; ++nf) {
        acc[m][nf] = __builtin_amdgcn_mfma_f32_16x16x32_f16(ah, b[nf], acc[m][nf], 0, 0, 0);
        acc[m][nf] = __builtin_amdgcn_mfma_f32_16x16x32_f16(ar, b[nf], acc[m][nf], 0, 0, 0);
      }
    }
  }

  // epilogue: col = lane&15 (n), row = (lane>>4)*4 + r (x).
  #pragma unroll
  for (int m = 0; m < 8; ++m) {
    int x0 = m * 16 + (lane >> 4) * 4;
    #pragma unroll
    for (int nf = 0; nf < 4; ++nf) {
      int n = n0 + wave * 64 + nf * 16 + (lane & 15);
      #pragma unroll
      for (int r = 0; r < 4; ++r)
        att[(size_t)(x0 + r) * BH + n] = (_Float16)acc[m][nf][r];
    }
  }
}

// --------------------------- final linear -----------------------------------
// out[32768,1024] = att @ linW^T + linb.  128x128 tile, BK=64, dbuf LDS.
__global__ __launch_bounds__(256) void k_final(const _Float16* __restrict__ att,
                                               const _Float16* __restrict__ Wl,
                                               const float* __restrict__ bvec,
                                               float* __restrict__ out) {
  __shared__ char smem[65536];
  const int tid = threadIdx.x, wave = tid >> 6, lane = tid & 63;
  const int m0 = (blockIdx.x >> 3) * 128;
  const int n0 = (blockIdx.x & 7) * 128;
  const int mh = (wave & 1) * 64, nh = (wave >> 1) * 64;

  f32x4 acc[4][4];
  #pragma unroll
  for (int i = 0; i < 4; ++i)
    #pragma unroll
    for (int j = 0; j < 4; ++j) acc[i][j] = (f32x4){0.f, 0.f, 0.f, 0.f};

  // LDS row = 128B = 8 chunks, swizzle c ^ (row & 7)
  auto stage = [&](int p, int k0) {
    char* base = smem + p * 32768;
    #pragma unroll
    for (int q = 0; q < 8; ++q) {
      int grp = q * 4 + wave;
      char* dst = base + grp * 1024;
      int s = grp * 64 + lane;
      if (s < 1024) {                      // A: 128 rows x 8 chunks
        int r = s >> 3, c = s & 7;
        int kc = c ^ (r & 7);
        g2l16(dst, att + (size_t)(m0 + r) * 1024 + k0 + kc * 8);
      } else {                             // B: 128 rows x 8 chunks
        int sb = s - 1024;
        int r = sb >> 3, c = sb & 7;
        int kc = c ^ (r & 7);
        g2l16(dst, Wl + (size_t)(n0 + r) * 1024 + k0 + kc * 8);
      }
    }
  };

  stage(0, 0);
  for (int iter = 0; iter < 16; ++iter) {
    int p = iter & 1;
    __syncthreads();
    if (iter + 1 < 16) stage(1 - p, (iter + 1) * 64);
    const char* At = smem + p * 32768;
    const char* Bt = At + 16384;
    #pragma unroll
    for (int k32 = 0; k32 < 2; ++k32) {
      int kc = k32 * 4 + (lane >> 4);      // 0..7
      half8 a[4], b[4];
      #pragma unroll
      for (int i = 0; i < 4; ++i) {
        int ra = mh + i * 16 + (lane & 15);
        a[i] = *(const half8*)(At + ra * 128 + ((kc ^ (ra & 7)) * 16));
        int rb = nh + i * 16 + (lane & 15);
        b[i] = *(const half8*)(Bt + rb * 128 + ((kc ^ (rb & 7)) * 16));
      }
      #pragma unroll
      for (int i = 0; i < 4; ++i)
        #pragma unroll
        for (int j = 0; j < 4; ++j)
          acc[i][j] = __builtin_amdgcn_mfma_f32_16x16x32_f16(a[i], b[j], acc[i][j], 0, 0, 0);
    }
  }

  #pragma unroll
  for (int i = 0; i < 4; ++i) {
    int m = m0 + mh + i * 16 + (lane >> 4) * 4;
    #pragma unroll
    for (int j = 0; j < 4; ++j) {
      int n = n0 + nh + j * 16 + (lane & 15);
      float bv = bvec[n];
      #pragma unroll
      for (int r = 0; r < 4; ++r)
        out[(size_t)(m + r) * 1024 + n] = acc[i][j][r] + bv;
    }
  }
}

// --------------------------- launch -----------------------------------------
extern "C" void kernel_launch(void* const* d_in, const int* in_sizes, int n_in,
                              void* d_out, int out_size, void* d_ws, size_t ws_size,
                              hipStream_t stream) {
  const float* X     = (const float*)d_in[0];
  const float* h0    = (const float*)d_in[1];
  const float* c0    = (const float*)d_in[2];
  const float* Wih   = (const float*)d_in[3];
  const float* Whh   = (const float*)d_in[4];
  const float* bih   = (const float*)d_in[5];
  const float* bhh   = (const float*)d_in[6];
  const float* attnW = (const float*)d_in[7];
  const float* linW  = (const float*)d_in[8];
  const float* linb  = (const float*)d_in[9];
  float* out = (float*)d_out;
  char* ws = (char*)d_ws;

  // workspace layout (bytes), ~212 MB total
  _Float16* Xh  = (_Float16*)(ws + 0);           // 67,108,864
  _Float16* Wc  = (_Float16*)(ws + 67108864);    // 16,777,216
  _Float16* Wl  = (_Float16*)(ws + 83886080);    //  2,097,152
  _Float16* hs  = (_Float16*)(ws + 85983232);    // 129 slots * 524,288
  _Float16* att = (_Float16*)(ws + 153616384);   // 67,108,864
  float* cbuf   = (float*)(ws + 220725248);      //  1,048,576
  float* bias   = (float*)(ws + 221773824);      //     16,384
  _Float16* Ahm = (_Float16*)(ws + 221790208);   //     32,768
  _Float16* Arm = (_Float16*)(ws + 221822976);   //     32,768

  k_cvt<<<16384, 256, 0, stream>>>(X, Xh);
  k_wcat<<<4096, 256, 0, stream>>>(Wih, Whh, Wc);
  k_cvt<<<512, 256, 0, stream>>>(linW, Wl);
  k_init<<<1024, 256, 0, stream>>>(h0, c0, bih, bhh, hs, cbuf, bias);
  k_softmax<<<128, 64, 0, stream>>>(attnW, Ahm, Arm);

  for (int t = 0; t < S_; ++t)
    k_step<<<256, 256, 0, stream>>>(Xh, Wc, bias, hs, cbuf, t);

  k_attn<<<1024, 256, 0, stream>>>(Ahm, Arm, hs, att);
  k_final<<<2048, 256, 0, stream>>>(att, Wl, linb, out);
}